// Round 6
// baseline (10953.568 us; speedup 1.0000x reference)
//
#include <hip/hip_runtime.h>
#include <cstdint>
#include <cstddef>

#define TSTEPS 100
#define NB 256
#define INF 2312
#define HIDN 512
#define NOUT 10

// ws layout (float offsets)
#define OFF_WT 0                  // 262144 floats (w_rec transposed, 1 MB)
#define OFF_CI 262144             // 13107200 floats (input-projection cache)
#define WS_FLOATS 13369344        // 53.5 MB

// build w_recT[j][h] = w_rec[h][j] (exact copy -> gather values unchanged)
__global__ __launch_bounds__(256) void init_kernel(float* __restrict__ wT,
                                                   const float* __restrict__ w_rec) {
    int m = blockIdx.x * 256 + threadIdx.x;   // m = j*512 + h
    if (m < HIDN * HIDN) {
        int j = m >> 9, h = m & 511;
        wT[m] = w_rec[h * HIDN + j];
    }
}

// C[r][h] = sum_k X[r][k] * Win[h][k]; per-element ascending-k fp64 FMA chain
// (ARITHMETIC FROZEN: identical to R1/R3/R5-passing kernels; downstream chaotic).
// 128x128 tile, 256 threads, 8x8 micro-tile + double-buffered reg-staged prefetch
// (scheduling only: global load of tile k+1 overlaps compute of tile k).
__global__ __launch_bounds__(256, 2) void gemm_in(const float* __restrict__ X,
                                                  const float* __restrict__ Win,
                                                  float* __restrict__ C) {
    __shared__ float As[32][136];   // [k][row], padded
    __shared__ float Bs[32][136];   // [k][col], padded
    const int tid = threadIdx.x;
    const int tx = tid & 15;             // cols tx*8..+7
    const int ty = tid >> 4;             // rows ty*8..+7
    const int row0 = blockIdx.y * 128, col0 = blockIdx.x * 128;
    const int sr = tid >> 1, sk = (tid & 1) * 16;   // staging: row/col, k-base
    float4 va[4], vb[4];
    // prologue: load tile k0=0 (gk = sk+q*4 <= 28 < INF, always in-bounds)
#pragma unroll
    for (int q = 0; q < 4; ++q) {
        int gk = sk + q * 4;
        va[q] = *(const float4*)(X + (size_t)(row0 + sr) * INF + gk);
        vb[q] = *(const float4*)(Win + (size_t)(col0 + sr) * INF + gk);
    }
    double acc[8][8] = {};
    for (int k0 = 0; k0 < INF; k0 += 32) {
        __syncthreads();   // previous compute done reading LDS
#pragma unroll
        for (int q = 0; q < 4; ++q) {
            int kc = sk + q * 4;
            As[kc + 0][sr] = va[q].x; As[kc + 1][sr] = va[q].y;
            As[kc + 2][sr] = va[q].z; As[kc + 3][sr] = va[q].w;
            Bs[kc + 0][sr] = vb[q].x; Bs[kc + 1][sr] = vb[q].y;
            Bs[kc + 2][sr] = vb[q].z; Bs[kc + 3][sr] = vb[q].w;
        }
        __syncthreads();
        // prefetch next tile into regs while computing this one
        const int kn = k0 + 32;
        if (kn < INF) {
#pragma unroll
            for (int q = 0; q < 4; ++q) {
                int gk = kn + sk + q * 4;
                float4 a = make_float4(0.f, 0.f, 0.f, 0.f);
                float4 b = make_float4(0.f, 0.f, 0.f, 0.f);
                if (gk < INF) {   // INF%4==0, gk%4==0 -> full float4 in-bounds
                    a = *(const float4*)(X + (size_t)(row0 + sr) * INF + gk);
                    b = *(const float4*)(Win + (size_t)(col0 + sr) * INF + gk);
                }
                va[q] = a; vb[q] = b;
            }
        }
#pragma unroll 4
        for (int kk = 0; kk < 32; ++kk) {
            float4 a0 = *(const float4*)&As[kk][ty * 8];
            float4 a1 = *(const float4*)&As[kk][ty * 8 + 4];
            float4 b0 = *(const float4*)&Bs[kk][tx * 8];
            float4 b1 = *(const float4*)&Bs[kk][tx * 8 + 4];
            double ad[8] = {(double)a0.x, (double)a0.y, (double)a0.z, (double)a0.w,
                            (double)a1.x, (double)a1.y, (double)a1.z, (double)a1.w};
            double bd[8] = {(double)b0.x, (double)b0.y, (double)b0.z, (double)b0.w,
                            (double)b1.x, (double)b1.y, (double)b1.z, (double)b1.w};
#pragma unroll
            for (int i = 0; i < 8; ++i)
#pragma unroll
                for (int j = 0; j < 8; ++j)
                    acc[i][j] += ad[i] * bd[j];
        }
    }
#pragma unroll
    for (int i = 0; i < 8; ++i) {
#pragma unroll
        for (int jj = 0; jj < 2; ++jj) {
            float4 o;
            o.x = (float)acc[i][jj * 4 + 0]; o.y = (float)acc[i][jj * 4 + 1];
            o.z = (float)acc[i][jj * 4 + 2]; o.w = (float)acc[i][jj * 4 + 3];
            *(float4*)(C + (size_t)(row0 + ty * 8 + i) * HIDN + col0 + tx * 8 + jj * 4) = o;
        }
    }
}

// Fused 100 steps, block = 2 batches, 128 blocks x 512 threads, thread = h.
// Gather now reads wT COLUMN h: lane l -> consecutive addresses = fully
// coalesced scalar loads (fixes R5's 64-line scatter). Per-element values
// VERBATIM R5: f = fadd_rn(f, bit ? w : 0.0f) ascending j within each 64-word,
// fp64 combine ascending word. One __syncthreads per step, no grid sync.
__global__ __launch_bounds__(512) void fused3(const float* __restrict__ ci,
        const float* __restrict__ wT, const float* __restrict__ w_out,
        float* __restrict__ out) {
    __shared__ unsigned long long zlds[2][2][8];   // [t&1][batch][wave]
    __shared__ float wout_s[NOUT * HIDN];          // 20 KB
    const int tid = threadIdx.x;
    const int wv = tid >> 6, lane = tid & 63;
    const int h = tid;
    const int b0 = (int)blockIdx.x * 2;
    const float* colp = wT + h;                    // thread's column base

    for (int i = tid; i < NOUT * HIDN; i += 512) wout_s[i] = w_out[i];
    __syncthreads();

    unsigned long long m0[8] = {0ull,0ull,0ull,0ull,0ull,0ull,0ull,0ull};
    unsigned long long m1[8] = {0ull,0ull,0ull,0ull,0ull,0ull,0ull,0ull};
    float pos0 = 0.f, pos1 = 0.f;
    const int og = wv >> 1, nb = wv & 1;           // wave -> (output-group, batch)
    const int nout_w = (og < 2) ? 3 : 2;           // o = og, og+4, og+8(<10)
    float vv[3] = {0.f, 0.f, 0.f}, ii[3] = {0.f, 0.f, 0.f};

    for (int t = 0; t < TSTEPS; ++t) {
        float civ0 = ci[((size_t)t * NB + b0) * HIDN + h];
        float civ1 = ci[((size_t)t * NB + b0 + 1) * HIDN + h];

        // ---- recurrent gather, coalesced transposed reads (frozen values) ----
        double acc0 = 0.0, acc1 = 0.0;
#pragma unroll
        for (int c2 = 0; c2 < 8; ++c2) {
            const unsigned long long um0 = m0[c2], um1 = m1[c2];
            const float* wp = colp + (size_t)(c2 << 6) * HIDN;
            float f0 = 0.f, f1 = 0.f;
#pragma unroll
            for (int jj = 0; jj < 64; ++jj) {
                float w = wp[(size_t)jj * HIDN];
                unsigned int ba = (unsigned int)(um0 >> jj) & 1u;
                unsigned int bb = (unsigned int)(um1 >> jj) & 1u;
                f0 = __fadd_rn(f0, ba ? w : 0.0f);
                f1 = __fadd_rn(f1, bb ? w : 0.0f);
            }
            acc0 += (double)f0;                    // ascending-word fp64 combine
            acc1 += (double)f1;
        }
        float rec0 = (float)acc0, rec1 = (float)acc1;

        // ---- membrane update + spike (frozen) ----
        float cur0 = __fadd_rn(__fadd_rn(civ0, rec0), 1e-4f);
        float mc0 = __fmul_rn(2.5e5f, cur0);
        pos0 = __fadd_rn(pos0, __fmul_rn(1e-10f, mc0));
        bool z0 = __fsub_rn(pos0, 2.5e-8f) > 0.0f;
        pos0 = z0 ? 0.0f : pos0;
        float cur1 = __fadd_rn(__fadd_rn(civ1, rec1), 1e-4f);
        float mc1 = __fmul_rn(2.5e5f, cur1);
        pos1 = __fadd_rn(pos1, __fmul_rn(1e-10f, mc1));
        bool z1 = __fsub_rn(pos1, 2.5e-8f) > 0.0f;
        pos1 = z1 ? 0.0f : pos1;

        unsigned long long bal0 = __ballot(z0 ? 1 : 0);
        unsigned long long bal1 = __ballot(z1 ? 1 : 0);
        if (lane == 0) {
            zlds[t & 1][0][wv] = bal0;
            zlds[t & 1][1][wv] = bal1;
        }
        __syncthreads();   // publish z_t (double-buffered in t -> one barrier/step)

        // ---- refresh uniform masks (SGPR) for LI + next gather ----
#pragma unroll
        for (int c2 = 0; c2 < 8; ++c2) {
            unsigned long long w0 = zlds[t & 1][0][c2];
            unsigned long long w1 = zlds[t & 1][1][c2];
            unsigned int l0 = __builtin_amdgcn_readfirstlane((unsigned int)w0);
            unsigned int h0 = __builtin_amdgcn_readfirstlane((unsigned int)(w0 >> 32));
            unsigned int l1 = __builtin_amdgcn_readfirstlane((unsigned int)w1);
            unsigned int h1 = __builtin_amdgcn_readfirstlane((unsigned int)(w1 >> 32));
            m0[c2] = ((unsigned long long)h0 << 32) | l0;
            m1[c2] = ((unsigned long long)h1 << 32) | l1;
        }

        // ---- LI readout for step t (frozen; wave -> batch nb, outputs og+4j) ----
#pragma unroll
        for (int j = 0; j < 3; ++j) {
            if (j < nout_w) {
                const int o = og + 4 * j;
                double part = 0.0;
#pragma unroll
                for (int c2 = 0; c2 < 8; ++c2) {
                    unsigned long long mb = nb ? m1[c2] : m0[c2];
                    if ((mb >> lane) & 1ull)
                        part += (double)wout_s[o * HIDN + (c2 << 6) + lane];
                }
#pragma unroll
                for (int off = 32; off > 0; off >>= 1) part += __shfl_down(part, off);
                if (lane == 0) {
                    float inp = (float)part;
                    float vn = __fadd_rn(vv[j], __fmul_rn(1e-8f, __fsub_rn(ii[j], vv[j])));
                    float t2 = __fmul_rn(2e-8f, ii[j]);
                    float in2 = __fadd_rn(__fsub_rn(ii[j], t2), inp);
                    vv[j] = vn; ii[j] = in2;
                    out[((size_t)t * NB + b0 + nb) * NOUT + o] = vn;
                }
            }
        }
    }
}

extern "C" void kernel_launch(void* const* d_in, const int* in_sizes, int n_in,
                              void* d_out, int out_size, void* d_ws, size_t ws_size,
                              hipStream_t stream) {
    (void)in_sizes; (void)n_in; (void)out_size;
    const float* x     = (const float*)d_in[0];
    const float* w_in  = (const float*)d_in[1];
    const float* w_rec = (const float*)d_in[2];
    const float* w_out = (const float*)d_in[3];
    float* out = (float*)d_out;
    float* ws  = (float*)d_ws;
    if (ws_size < (size_t)WS_FLOATS * 4) return;

    float* wT = ws + OFF_WT;
    float* ci = ws + OFF_CI;

    hipLaunchKernelGGL(init_kernel, dim3((HIDN * HIDN + 255) / 256), dim3(256), 0,
                       stream, wT, w_rec);
    hipLaunchKernelGGL(gemm_in, dim3(4, 200), dim3(256), 0, stream, x, w_in, ci);
    hipLaunchKernelGGL(fused3, dim3(NB / 2), dim3(512), 0, stream,
                       ci, wT, w_out, out);
}

// Round 7
// 8846.959 us; speedup vs baseline: 1.2381x; 1.2381x over previous
//
#include <hip/hip_runtime.h>
#include <cstdint>
#include <cstddef>

#define TSTEPS 100
#define NB 256
#define INF 2312
#define HIDN 512
#define NOUT 10

// ws layout (float offsets)
#define OFF_WT 0                  // 262144 floats (w_rec transposed, 1 MB)
#define OFF_CI 262144             // 13107200 floats (input-projection cache)
#define WS_FLOATS 13369344        // 53.5 MB

// build w_recT[j][h] = w_rec[h][j] (exact copy -> gather values unchanged)
__global__ __launch_bounds__(256) void init_kernel(float* __restrict__ wT,
                                                   const float* __restrict__ w_rec) {
    int m = blockIdx.x * 256 + threadIdx.x;   // m = j*512 + h
    if (m < HIDN * HIDN) {
        int j = m >> 9, h = m & 511;
        wT[m] = w_rec[h * HIDN + j];
    }
}

// C[r][h] = sum_k X[r][k] * Win[h][k]; per-element ascending-k fp64 FMA chain
// (ARITHMETIC FROZEN: identical to R1/R3/R5/R6-passing kernels). VERBATIM R6.
__global__ __launch_bounds__(256, 2) void gemm_in(const float* __restrict__ X,
                                                  const float* __restrict__ Win,
                                                  float* __restrict__ C) {
    __shared__ float As[32][136];   // [k][row], padded
    __shared__ float Bs[32][136];   // [k][col], padded
    const int tid = threadIdx.x;
    const int tx = tid & 15;             // cols tx*8..+7
    const int ty = tid >> 4;             // rows ty*8..+7
    const int row0 = blockIdx.y * 128, col0 = blockIdx.x * 128;
    const int sr = tid >> 1, sk = (tid & 1) * 16;   // staging: row/col, k-base
    float4 va[4], vb[4];
#pragma unroll
    for (int q = 0; q < 4; ++q) {
        int gk = sk + q * 4;
        va[q] = *(const float4*)(X + (size_t)(row0 + sr) * INF + gk);
        vb[q] = *(const float4*)(Win + (size_t)(col0 + sr) * INF + gk);
    }
    double acc[8][8] = {};
    for (int k0 = 0; k0 < INF; k0 += 32) {
        __syncthreads();
#pragma unroll
        for (int q = 0; q < 4; ++q) {
            int kc = sk + q * 4;
            As[kc + 0][sr] = va[q].x; As[kc + 1][sr] = va[q].y;
            As[kc + 2][sr] = va[q].z; As[kc + 3][sr] = va[q].w;
            Bs[kc + 0][sr] = vb[q].x; Bs[kc + 1][sr] = vb[q].y;
            Bs[kc + 2][sr] = vb[q].z; Bs[kc + 3][sr] = vb[q].w;
        }
        __syncthreads();
        const int kn = k0 + 32;
        if (kn < INF) {
#pragma unroll
            for (int q = 0; q < 4; ++q) {
                int gk = kn + sk + q * 4;
                float4 a = make_float4(0.f, 0.f, 0.f, 0.f);
                float4 b = make_float4(0.f, 0.f, 0.f, 0.f);
                if (gk < INF) {
                    a = *(const float4*)(X + (size_t)(row0 + sr) * INF + gk);
                    b = *(const float4*)(Win + (size_t)(col0 + sr) * INF + gk);
                }
                va[q] = a; vb[q] = b;
            }
        }
#pragma unroll 4
        for (int kk = 0; kk < 32; ++kk) {
            float4 a0 = *(const float4*)&As[kk][ty * 8];
            float4 a1 = *(const float4*)&As[kk][ty * 8 + 4];
            float4 b0 = *(const float4*)&Bs[kk][tx * 8];
            float4 b1 = *(const float4*)&Bs[kk][tx * 8 + 4];
            double ad[8] = {(double)a0.x, (double)a0.y, (double)a0.z, (double)a0.w,
                            (double)a1.x, (double)a1.y, (double)a1.z, (double)a1.w};
            double bd[8] = {(double)b0.x, (double)b0.y, (double)b0.z, (double)b0.w,
                            (double)b1.x, (double)b1.y, (double)b1.z, (double)b1.w};
#pragma unroll
            for (int i = 0; i < 8; ++i)
#pragma unroll
                for (int j = 0; j < 8; ++j)
                    acc[i][j] += ad[i] * bd[j];
        }
    }
#pragma unroll
    for (int i = 0; i < 8; ++i) {
#pragma unroll
        for (int jj = 0; jj < 2; ++jj) {
            float4 o;
            o.x = (float)acc[i][jj * 4 + 0]; o.y = (float)acc[i][jj * 4 + 1];
            o.z = (float)acc[i][jj * 4 + 2]; o.w = (float)acc[i][jj * 4 + 3];
            *(float4*)(C + (size_t)(row0 + ty * 8 + i) * HIDN + col0 + tx * 8 + jj * 4) = o;
        }
    }
}

// Fused 100 steps, block = ONE batch (256 blocks = 1/CU), 1024 threads =
// 512 h x 2 j-halves. Each thread holds 256 w_rec weights IN REGISTERS
// (wreg[4][64], static indexing only) -> the gather does ZERO memory loads.
// j-half partials exchanged via LDS; fp64 fold stays the exact ascending
// word-order chain (words 0..7). Select-add values VERBATIM R5/R6 (proven
// bit-exact). Block-local z via LDS ballots, 2 barriers/step, no grid sync.
__global__ __launch_bounds__(1024) void fused_reg(const float* __restrict__ ci,
        const float* __restrict__ wT, const float* __restrict__ w_out,
        float* __restrict__ out) {
    __shared__ unsigned long long zlds[2][8];      // [t&1][word]
    __shared__ float fx[HIDN][4];                  // jh1 partials, 8 KB
    __shared__ float wout_s[NOUT * HIDN];          // 20 KB
    const int tid = threadIdx.x;
    const int h = tid & 511, jh = tid >> 9;        // jh: words jh*4 .. jh*4+3
    const int wv = tid >> 6, lane = tid & 63;
    const int b = blockIdx.x;

    // one-time weight preload: wreg[q64][qq] = w_rec[h][jh*256 + q64*64 + qq]
    float wreg[4][64];
#pragma unroll
    for (int q64 = 0; q64 < 4; ++q64)
#pragma unroll
        for (int qq = 0; qq < 64; ++qq)
            wreg[q64][qq] = wT[(size_t)(jh * 256 + q64 * 64 + qq) * HIDN + h];

    for (int i = tid; i < NOUT * HIDN; i += 1024) wout_s[i] = w_out[i];
    if (tid < 16) ((unsigned long long*)zlds)[tid] = 0ull;
    __syncthreads();

    unsigned long long m[8] = {0ull,0ull,0ull,0ull,0ull,0ull,0ull,0ull};
    float pos = 0.0f;
    float v0 = 0.f, i0 = 0.f, v1 = 0.f, i1 = 0.f;  // LI state (lane 0, waves 0-7)

    for (int t = 0; t < TSTEPS; ++t) {
        // ---- register gather: 4 per-word f32 chains (frozen values) ----
        float fv[4];
#pragma unroll
        for (int q64 = 0; q64 < 4; ++q64) {
            const unsigned long long um = jh ? m[4 + q64] : m[q64];
            float f = 0.0f;
#pragma unroll
            for (int qq = 0; qq < 64; ++qq)
                f = __fadd_rn(f, ((um >> qq) & 1ull) ? wreg[q64][qq] : 0.0f);
            fv[q64] = f;
        }
        if (jh) {
            fx[h][0] = fv[0]; fx[h][1] = fv[1];
            fx[h][2] = fv[2]; fx[h][3] = fv[3];
        }
        __syncthreads();   // barrier A: partials published

        if (!jh) {
            // exact ascending word fold (0..7), same chain as R5/R6
            double acc = 0.0;
            acc += (double)fv[0]; acc += (double)fv[1];
            acc += (double)fv[2]; acc += (double)fv[3];
            acc += (double)fx[h][0]; acc += (double)fx[h][1];
            acc += (double)fx[h][2]; acc += (double)fx[h][3];
            float rec32 = (float)acc;

            float civ = ci[((size_t)t * NB + b) * HIDN + h];
            float cur = __fadd_rn(__fadd_rn(civ, rec32), 1e-4f);   // (in+rec)+I_APP
            float mc = __fmul_rn(2.5e5f, cur);                     // MU*cur
            pos = __fadd_rn(pos, __fmul_rn(1e-10f, mc));           // pos += DT*(..)
            bool zbit = __fsub_rn(pos, 2.5e-8f) > 0.0f;            // pos-W2 > 0
            pos = zbit ? 0.0f : pos;
            unsigned long long bal = __ballot(zbit ? 1 : 0);
            if (lane == 0) zlds[t & 1][wv] = bal;
        }
        __syncthreads();   // barrier B: z_t published

        // ---- refresh uniform masks (SGPR) ----
#pragma unroll
        for (int c2 = 0; c2 < 8; ++c2) {
            unsigned long long w = zlds[t & 1][c2];
            unsigned int lo = __builtin_amdgcn_readfirstlane((unsigned int)w);
            unsigned int hi = __builtin_amdgcn_readfirstlane((unsigned int)(w >> 32));
            m[c2] = ((unsigned long long)hi << 32) | lo;
        }

        // ---- LI readout for step t (VERBATIM R3 arithmetic; waves 0-7) ----
        if (!jh) {
#pragma unroll
            for (int oo = 0; oo < 2; ++oo) {
                int o = (oo == 0) ? wv : (wv < 2 ? 8 + wv : -1);
                if (o < 0) continue;
                double part = 0.0;
#pragma unroll
                for (int c2 = 0; c2 < 8; ++c2) {
                    if ((m[c2] >> lane) & 1ull)
                        part += (double)wout_s[o * HIDN + (c2 << 6) + lane];
                }
#pragma unroll
                for (int off = 32; off > 0; off >>= 1) part += __shfl_down(part, off);
                if (lane == 0) {
                    float inp = (float)part;
                    float vv = (oo == 0) ? v0 : v1;
                    float ii = (oo == 0) ? i0 : i1;
                    float vn = __fadd_rn(vv, __fmul_rn(1e-8f, __fsub_rn(ii, vv)));
                    float t2 = __fmul_rn(2e-8f, ii);
                    float in2 = __fadd_rn(__fsub_rn(ii, t2), inp);
                    if (oo == 0) { v0 = vn; i0 = in2; } else { v1 = vn; i1 = in2; }
                    out[((size_t)t * NB + b) * NOUT + o] = vn;
                }
            }
        }
    }
}

extern "C" void kernel_launch(void* const* d_in, const int* in_sizes, int n_in,
                              void* d_out, int out_size, void* d_ws, size_t ws_size,
                              hipStream_t stream) {
    (void)in_sizes; (void)n_in; (void)out_size;
    const float* x     = (const float*)d_in[0];
    const float* w_in  = (const float*)d_in[1];
    const float* w_rec = (const float*)d_in[2];
    const float* w_out = (const float*)d_in[3];
    float* out = (float*)d_out;
    float* ws  = (float*)d_ws;
    if (ws_size < (size_t)WS_FLOATS * 4) return;

    float* wT = ws + OFF_WT;
    float* ci = ws + OFF_CI;

    hipLaunchKernelGGL(init_kernel, dim3((HIDN * HIDN + 255) / 256), dim3(256), 0,
                       stream, wT, w_rec);
    hipLaunchKernelGGL(gemm_in, dim3(4, 200), dim3(256), 0, stream, x, w_in, ci);
    hipLaunchKernelGGL(fused_reg, dim3(NB), dim3(1024), 0, stream,
                       ci, wT, w_out, out);
}

// Round 8
// 4862.541 us; speedup vs baseline: 2.2526x; 1.8194x over previous
//
#include <hip/hip_runtime.h>
#include <cstdint>
#include <cstddef>

#define TSTEPS 100
#define NB 256
#define INF 2312
#define HIDN 512
#define NOUT 10

// ws layout (float offsets)
#define OFF_WT  0                 // 262144 floats (w_rec transposed, 1 MB)
#define OFF_ZB  262144            // 8192 floats = [2][32][8][8] u64 ballots
#define OFF_CTR 270336            // 1024 u32: 32 group counters, 128B apart
#define OFF_CI  271360            // 13107200 floats (input-projection cache)
#define WS_FLOATS 13378560        // 53.5 MB

// build w_recT[j][h] = w_rec[h][j]; zero ballot buffers + group counters
__global__ __launch_bounds__(256) void init_kernel(float* __restrict__ ws,
                                                   const float* __restrict__ w_rec) {
    int n = blockIdx.x * 256 + threadIdx.x;
    if (n < HIDN * HIDN) {
        int j = n >> 9, h = n & 511;
        ws[n] = w_rec[h * HIDN + j];
    } else if (n < OFF_CI) {
        ws[n] = 0.0f;
    }
}

// C[r][h] = sum_k X[r][k] * Win[h][k]; per-element ascending-k fp64 FMA chain
// (ARITHMETIC FROZEN: identical to R1/R3/R5/R6/R7-passing kernels). VERBATIM R6.
__global__ __launch_bounds__(256, 2) void gemm_in(const float* __restrict__ X,
                                                  const float* __restrict__ Win,
                                                  float* __restrict__ C) {
    __shared__ float As[32][136];   // [k][row], padded
    __shared__ float Bs[32][136];   // [k][col], padded
    const int tid = threadIdx.x;
    const int tx = tid & 15;             // cols tx*8..+7
    const int ty = tid >> 4;             // rows ty*8..+7
    const int row0 = blockIdx.y * 128, col0 = blockIdx.x * 128;
    const int sr = tid >> 1, sk = (tid & 1) * 16;   // staging: row/col, k-base
    float4 va[4], vb[4];
#pragma unroll
    for (int q = 0; q < 4; ++q) {
        int gk = sk + q * 4;
        va[q] = *(const float4*)(X + (size_t)(row0 + sr) * INF + gk);
        vb[q] = *(const float4*)(Win + (size_t)(col0 + sr) * INF + gk);
    }
    double acc[8][8] = {};
    for (int k0 = 0; k0 < INF; k0 += 32) {
        __syncthreads();
#pragma unroll
        for (int q = 0; q < 4; ++q) {
            int kc = sk + q * 4;
            As[kc + 0][sr] = va[q].x; As[kc + 1][sr] = va[q].y;
            As[kc + 2][sr] = va[q].z; As[kc + 3][sr] = va[q].w;
            Bs[kc + 0][sr] = vb[q].x; Bs[kc + 1][sr] = vb[q].y;
            Bs[kc + 2][sr] = vb[q].z; Bs[kc + 3][sr] = vb[q].w;
        }
        __syncthreads();
        const int kn = k0 + 32;
        if (kn < INF) {
#pragma unroll
            for (int q = 0; q < 4; ++q) {
                int gk = kn + sk + q * 4;
                float4 a = make_float4(0.f, 0.f, 0.f, 0.f);
                float4 b = make_float4(0.f, 0.f, 0.f, 0.f);
                if (gk < INF) {
                    a = *(const float4*)(X + (size_t)(row0 + sr) * INF + gk);
                    b = *(const float4*)(Win + (size_t)(col0 + sr) * INF + gk);
                }
                va[q] = a; vb[q] = b;
            }
        }
#pragma unroll 4
        for (int kk = 0; kk < 32; ++kk) {
            float4 a0 = *(const float4*)&As[kk][ty * 8];
            float4 a1 = *(const float4*)&As[kk][ty * 8 + 4];
            float4 b0 = *(const float4*)&Bs[kk][tx * 8];
            float4 b1 = *(const float4*)&Bs[kk][tx * 8 + 4];
            double ad[8] = {(double)a0.x, (double)a0.y, (double)a0.z, (double)a0.w,
                            (double)a1.x, (double)a1.y, (double)a1.z, (double)a1.w};
            double bd[8] = {(double)b0.x, (double)b0.y, (double)b0.z, (double)b0.w,
                            (double)b1.x, (double)b1.y, (double)b1.z, (double)b1.w};
#pragma unroll
            for (int i = 0; i < 8; ++i)
#pragma unroll
                for (int j = 0; j < 8; ++j)
                    acc[i][j] += ad[i] * bd[j];
        }
    }
#pragma unroll
    for (int i = 0; i < 8; ++i) {
#pragma unroll
        for (int jj = 0; jj < 2; ++jj) {
            float4 o;
            o.x = (float)acc[i][jj * 4 + 0]; o.y = (float)acc[i][jj * 4 + 1];
            o.z = (float)acc[i][jj * 4 + 2]; o.w = (float)acc[i][jj * 4 + 3];
            *(float4*)(C + (size_t)(row0 + ty * 8 + i) * HIDN + col0 + tx * 8 + jj * 4) = o;
        }
    }
}

// Persistent fused stepper. 256 blocks = 32 groups x 8 h-chunks; block =
// (8 batches) x (64-h chunk), 512 threads. Weights for the chunk (512j x 64h,
// 128 KB) LDS-resident. Gather: wave = j-word, lane = h; one conflict-free
// ds_read per j reused for 8 batches via fmac(mult in {0,1}) — bit-identical
// to the frozen select-add chain. z exchange: 64 B/group via agent atomics +
// GROUP-LOCAL 8-block barrier (32 independent counters). Frozen fp ops verbatim.
__global__ __launch_bounds__(512) void fused_lds(const float* __restrict__ ci,
        const float* __restrict__ wT, const float* __restrict__ w_out,
        float* __restrict__ out, unsigned long long* __restrict__ zbuf,
        unsigned int* __restrict__ ctr) {
    __shared__ float wsl[512 * 64];               // [j][h] 128 KB
    __shared__ float fbuf[8 * 64 * 9];            // [word][h][b] padded, 18 KB
    __shared__ float wout2[2][512];               // rows o=c, o=8+c
    __shared__ unsigned long long zsh[8][8];      // [b][word]
    const int tid = threadIdx.x;
    const int wv = tid >> 6, lane = tid & 63;
    // XCD-friendly remap (perf guess only): group members share blockIdx%8
    const int i = (int)blockIdx.x;
    const int c = (i >> 3) & 7;                           // h-chunk / member
    const int g = (i & 7) | ((i >> 6) << 3);              // group 0..31
    const int b0 = g * 8;

    // stage chunk weights: wsl[j][h] = wT[j][c*64+h]
    for (int idx = tid; idx < 512 * 64; idx += 512) {
        int j = idx >> 6, hh = idx & 63;
        wsl[idx] = wT[(size_t)j * HIDN + (c << 6) + hh];
    }
    if (tid < 512) {
        wout2[0][tid] = w_out[c * HIDN + tid];
        wout2[1][tid] = (c < 2) ? w_out[(8 + c) * HIDN + tid] : 0.0f;
    }
    if (tid < 64) zsh[tid >> 3][tid & 7] = 0ull;
    __syncthreads();

    unsigned long long* zbA = zbuf + (size_t)g * 64;          // [b8][word]
    unsigned long long* zbB = zbuf + 2048 + (size_t)g * 64;
    unsigned int* myctr = ctr + g * 32;                       // 128B apart

    float pos = 0.0f;                 // fold-phase: thread = (batch wv, h lane)
    float vA = 0.f, iA = 0.f, vB = 0.f, iB = 0.f;   // LI state on lane 0

    for (int t = 0; t < TSTEPS; ++t) {
        // ---- uniform gather masks: word wv of each batch (z from t-1) ----
        unsigned long long gm[8];
#pragma unroll
        for (int b = 0; b < 8; ++b) {
            unsigned long long w = zsh[b][wv];
            unsigned int lo = __builtin_amdgcn_readfirstlane((unsigned int)w);
            unsigned int hi = __builtin_amdgcn_readfirstlane((unsigned int)(w >> 32));
            gm[b] = ((unsigned long long)hi << 32) | lo;
        }

        // ---- dense gather: f[b] = frozen per-word chain, ascending qq ----
        float f[8] = {0.f, 0.f, 0.f, 0.f, 0.f, 0.f, 0.f, 0.f};
#pragma unroll 8
        for (int qq = 0; qq < 64; ++qq) {
            float w = wsl[(((wv << 6) + qq) << 6) + lane];
#pragma unroll
            for (int b = 0; b < 8; ++b)
                f[b] = __fmaf_rn(((gm[b] >> qq) & 1ull) ? 1.0f : 0.0f, w, f[b]);
        }
#pragma unroll
        for (int b = 0; b < 8; ++b)
            fbuf[(((wv << 6) + lane) * 9) + b] = f[b];
        __syncthreads();

        // ---- fold + neuron update (frozen): thread = (batch wv, h lane) ----
        double acc = 0.0;
#pragma unroll
        for (int c2 = 0; c2 < 8; ++c2)
            acc += (double)fbuf[(((c2 << 6) + lane) * 9) + wv];
        float rec32 = (float)acc;
        float civ = ci[((size_t)t * NB + (b0 + wv)) * HIDN + (c << 6) + lane];
        float cur = __fadd_rn(__fadd_rn(civ, rec32), 1e-4f);   // (in+rec)+I_APP
        float mc = __fmul_rn(2.5e5f, cur);                     // MU*cur
        pos = __fadd_rn(pos, __fmul_rn(1e-10f, mc));           // pos += DT*(..)
        bool zbit = __fsub_rn(pos, 2.5e-8f) > 0.0f;            // pos-W2 > 0
        pos = zbit ? 0.0f : pos;
        unsigned long long bal = __ballot(zbit ? 1 : 0);
        unsigned long long* zw = (t & 1) ? zbB : zbA;
        if (lane == 0)
            __hip_atomic_store(&zw[wv * 8 + c], bal, __ATOMIC_RELEASE,
                               __HIP_MEMORY_SCOPE_AGENT);
        __syncthreads();

        // ---- group-local 8-block barrier ----
        if (tid == 0) {
            __hip_atomic_fetch_add(myctr, 1u, __ATOMIC_ACQ_REL,
                                   __HIP_MEMORY_SCOPE_AGENT);
            const unsigned int tgt = 8u * (unsigned)(t + 1);
            while (__hip_atomic_load(myctr, __ATOMIC_ACQUIRE,
                                     __HIP_MEMORY_SCOPE_AGENT) < tgt)
                __builtin_amdgcn_s_sleep(2);
        }
        __syncthreads();

        // ---- pull group's z_t (64 u64, agent scope bypasses L1) ----
        if (tid < 64)
            zsh[tid >> 3][tid & 7] =
                __hip_atomic_load(&zw[tid], __ATOMIC_ACQUIRE,
                                  __HIP_MEMORY_SCOPE_AGENT);
        __syncthreads();

        // ---- LI readout for step t (frozen chain): wave = batch ----
        unsigned long long mli[8];
        {
            unsigned long long wl = (lane < 8) ? zsh[wv][lane] : 0ull;
            unsigned int wlo = (unsigned int)wl, whi = (unsigned int)(wl >> 32);
#pragma unroll
            for (int c2 = 0; c2 < 8; ++c2) {
                unsigned int lo = (unsigned int)__shfl((int)wlo, c2);
                unsigned int hi = (unsigned int)__shfl((int)whi, c2);
                lo = __builtin_amdgcn_readfirstlane(lo);
                hi = __builtin_amdgcn_readfirstlane(hi);
                mli[c2] = ((unsigned long long)hi << 32) | lo;
            }
        }
#pragma unroll
        for (int oo = 0; oo < 2; ++oo) {
            int o = (oo == 0) ? c : (c < 2 ? 8 + c : -1);
            if (o < 0) continue;
            double part = 0.0;
#pragma unroll
            for (int c2 = 0; c2 < 8; ++c2) {
                if ((mli[c2] >> lane) & 1ull)
                    part += (double)wout2[oo][(c2 << 6) + lane];
            }
#pragma unroll
            for (int off = 32; off > 0; off >>= 1) part += __shfl_down(part, off);
            if (lane == 0) {
                float inp = (float)part;
                float vvv = (oo == 0) ? vA : vB;
                float iiv = (oo == 0) ? iA : iB;
                float vn = __fadd_rn(vvv, __fmul_rn(1e-8f, __fsub_rn(iiv, vvv)));
                float t2 = __fmul_rn(2e-8f, iiv);
                float in2 = __fadd_rn(__fsub_rn(iiv, t2), inp);
                if (oo == 0) { vA = vn; iA = in2; } else { vB = vn; iB = in2; }
                out[((size_t)t * NB + (b0 + wv)) * NOUT + o] = vn;
            }
        }
    }
}

extern "C" void kernel_launch(void* const* d_in, const int* in_sizes, int n_in,
                              void* d_out, int out_size, void* d_ws, size_t ws_size,
                              hipStream_t stream) {
    (void)in_sizes; (void)n_in; (void)out_size;
    const float* x     = (const float*)d_in[0];
    const float* w_in  = (const float*)d_in[1];
    const float* w_rec = (const float*)d_in[2];
    const float* w_out = (const float*)d_in[3];
    float* out = (float*)d_out;
    float* ws  = (float*)d_ws;
    if (ws_size < (size_t)WS_FLOATS * 4) return;

    float* wT = ws + OFF_WT;
    unsigned long long* zbuf = (unsigned long long*)(ws + OFF_ZB);
    unsigned int* ctr = (unsigned int*)(ws + OFF_CTR);
    float* ci = ws + OFF_CI;

    hipLaunchKernelGGL(init_kernel, dim3((OFF_CI + 255) / 256), dim3(256), 0,
                       stream, ws, w_rec);
    hipLaunchKernelGGL(gemm_in, dim3(4, 200), dim3(256), 0, stream, x, w_in, ci);
    hipLaunchKernelGGL(fused_lds, dim3(NB), dim3(512), 0, stream,
                       ci, wT, w_out, out, zbuf, ctr);
}

// Round 9
// 2707.975 us; speedup vs baseline: 4.0449x; 1.7956x over previous
//
#include <hip/hip_runtime.h>
#include <cstdint>
#include <cstddef>

#define TSTEPS 100
#define NB 256
#define INF 2312
#define HIDN 512
#define NOUT 10

// ws layout (float offsets)
#define OFF_WT  0                 // 262144 floats (w_rec transposed, 1 MB)
#define OFF_ZB  262144            // 65536 floats = [2][256][512] u8 z-transit
#define OFF_CTR 327680            // 1024 u32: 32 group counters, 128B apart
#define OFF_CI  328704            // 13107200 floats (input-projection cache)
#define WS_FLOATS 13435904        // 53.7 MB (<= R1's accepted 54.05 MB)

// build w_recT[j][h] = w_rec[h][j]; zero z-transit + group counters
__global__ __launch_bounds__(256) void init_kernel(float* __restrict__ ws,
                                                   const float* __restrict__ w_rec) {
    int n = blockIdx.x * 256 + threadIdx.x;
    if (n < HIDN * HIDN) {
        int j = n >> 9, h = n & 511;
        ws[n] = w_rec[h * HIDN + j];
    } else if (n < OFF_CI) {
        ws[n] = 0.0f;
    }
}

// C[r][h] = sum_k X[r][k] * Win[h][k]; per-element ascending-k fp64 FMA chain
// (ARITHMETIC FROZEN: identical to all passing rounds). VERBATIM R6/R8.
__global__ __launch_bounds__(256, 2) void gemm_in(const float* __restrict__ X,
                                                  const float* __restrict__ Win,
                                                  float* __restrict__ C) {
    __shared__ float As[32][136];   // [k][row], padded
    __shared__ float Bs[32][136];   // [k][col], padded
    const int tid = threadIdx.x;
    const int tx = tid & 15;             // cols tx*8..+7
    const int ty = tid >> 4;             // rows ty*8..+7
    const int row0 = blockIdx.y * 128, col0 = blockIdx.x * 128;
    const int sr = tid >> 1, sk = (tid & 1) * 16;   // staging: row/col, k-base
    float4 va[4], vb[4];
#pragma unroll
    for (int q = 0; q < 4; ++q) {
        int gk = sk + q * 4;
        va[q] = *(const float4*)(X + (size_t)(row0 + sr) * INF + gk);
        vb[q] = *(const float4*)(Win + (size_t)(col0 + sr) * INF + gk);
    }
    double acc[8][8] = {};
    for (int k0 = 0; k0 < INF; k0 += 32) {
        __syncthreads();
#pragma unroll
        for (int q = 0; q < 4; ++q) {
            int kc = sk + q * 4;
            As[kc + 0][sr] = va[q].x; As[kc + 1][sr] = va[q].y;
            As[kc + 2][sr] = va[q].z; As[kc + 3][sr] = va[q].w;
            Bs[kc + 0][sr] = vb[q].x; Bs[kc + 1][sr] = vb[q].y;
            Bs[kc + 2][sr] = vb[q].z; Bs[kc + 3][sr] = vb[q].w;
        }
        __syncthreads();
        const int kn = k0 + 32;
        if (kn < INF) {
#pragma unroll
            for (int q = 0; q < 4; ++q) {
                int gk = kn + sk + q * 4;
                float4 a = make_float4(0.f, 0.f, 0.f, 0.f);
                float4 b = make_float4(0.f, 0.f, 0.f, 0.f);
                if (gk < INF) {
                    a = *(const float4*)(X + (size_t)(row0 + sr) * INF + gk);
                    b = *(const float4*)(Win + (size_t)(col0 + sr) * INF + gk);
                }
                va[q] = a; vb[q] = b;
            }
        }
#pragma unroll 4
        for (int kk = 0; kk < 32; ++kk) {
            float4 a0 = *(const float4*)&As[kk][ty * 8];
            float4 a1 = *(const float4*)&As[kk][ty * 8 + 4];
            float4 b0 = *(const float4*)&Bs[kk][tx * 8];
            float4 b1 = *(const float4*)&Bs[kk][tx * 8 + 4];
            double ad[8] = {(double)a0.x, (double)a0.y, (double)a0.z, (double)a0.w,
                            (double)a1.x, (double)a1.y, (double)a1.z, (double)a1.w};
            double bd[8] = {(double)b0.x, (double)b0.y, (double)b0.z, (double)b0.w,
                            (double)b1.x, (double)b1.y, (double)b1.z, (double)b1.w};
#pragma unroll
            for (int i = 0; i < 8; ++i)
#pragma unroll
                for (int j = 0; j < 8; ++j)
                    acc[i][j] += ad[i] * bd[j];
        }
    }
#pragma unroll
    for (int i = 0; i < 8; ++i) {
#pragma unroll
        for (int jj = 0; jj < 2; ++jj) {
            float4 o;
            o.x = (float)acc[i][jj * 4 + 0]; o.y = (float)acc[i][jj * 4 + 1];
            o.z = (float)acc[i][jj * 4 + 2]; o.w = (float)acc[i][jj * 4 + 3];
            *(float4*)(C + (size_t)(row0 + ty * 8 + i) * HIDN + col0 + tx * 8 + jj * 4) = o;
        }
    }
}

// Persistent fused stepper, SALU-free gather. 256 blocks = 32 groups x 8
// h-chunks (group members co-XCD); block = 8 batches x 64-h chunk, 512 thr.
// Thread (word wv, h lane) holds its 64 w_rec weights in VGPRs (static idx).
// Spikes travel as floats {0,1}: LDS zf[8][512] (union'd with fold partials),
// u8 global transit. Gather = pure v_fmac chains (frozen: fma(zf,w,f) is
// bit-identical to the select-add chain). LI uses fp64 fma(zf,w,part) —
// single rounding == frozen conditional add. Group barrier as in R8.
__global__ __launch_bounds__(512) void fused_zf(const float* __restrict__ ci,
        const float* __restrict__ wT, const float* __restrict__ w_out,
        float* __restrict__ out, unsigned char* __restrict__ zb,
        unsigned int* __restrict__ ctr) {
    __shared__ float zfb[4096];        // 16 KB union: zf[b][j] | fbufT[c2][b][h]
    __shared__ float wout2[2][512];    // 4 KB
    const int tid = threadIdx.x;
    const int wv = tid >> 6, lane = tid & 63;
    const int i = (int)blockIdx.x;
    const int c = (i >> 3) & 7;                    // h-chunk / group member
    const int g = (i & 7) | ((i >> 6) << 3);       // group 0..31 (co-XCD)
    const int b0 = g * 8;

    // one-time: 64 resident weights w[wv*64+qq][c*64+lane]
    float wreg[64];
#pragma unroll
    for (int qq = 0; qq < 64; ++qq)
        wreg[qq] = wT[(size_t)((wv << 6) + qq) * HIDN + (c << 6) + lane];

    if (tid < 512) {
        wout2[0][tid] = w_out[c * HIDN + tid];
        wout2[1][tid] = (c < 2) ? w_out[(8 + c) * HIDN + tid] : 0.0f;
    }
    for (int idx = tid; idx < 4096; idx += 512) zfb[idx] = 0.0f;  // z_{-1}=0
    __syncthreads();

    unsigned char* zbA = zb + (size_t)b0 * HIDN;            // [b][j] u8
    unsigned char* zbB = zb + 131072 + (size_t)b0 * HIDN;
    unsigned int* myctr = ctr + g * 32;                     // 128B apart

    float pos = 0.0f;                  // fold phase: thread = (batch wv, h lane)
    float vA = 0.f, iA = 0.f, vB = 0.f, iB = 0.f;   // LI state on lane 0

    for (int t = 0; t < TSTEPS; ++t) {
        // ---- gather: thread (word wv, h lane); zf broadcasts + fmac chains.
        // qq ascending per chain b (frozen order); b-interleaved for ILP.
        float f[8] = {0.f, 0.f, 0.f, 0.f, 0.f, 0.f, 0.f, 0.f};
#pragma unroll
        for (int q4 = 0; q4 < 16; ++q4) {
            float4 z4[8];
#pragma unroll
            for (int b = 0; b < 8; ++b)
                z4[b] = *(const float4*)&zfb[b * 512 + (wv << 6) + q4 * 4];
#pragma unroll
            for (int b = 0; b < 8; ++b) {
                f[b] = __fmaf_rn(z4[b].x, wreg[q4 * 4 + 0], f[b]);
                f[b] = __fmaf_rn(z4[b].y, wreg[q4 * 4 + 1], f[b]);
                f[b] = __fmaf_rn(z4[b].z, wreg[q4 * 4 + 2], f[b]);
                f[b] = __fmaf_rn(z4[b].w, wreg[q4 * 4 + 3], f[b]);
            }
        }
        __syncthreads();   // B1: all zf reads done; region becomes fbufT
#pragma unroll
        for (int b = 0; b < 8; ++b)
            zfb[((wv << 3) + b) * 64 + lane] = f[b];   // fbufT[c2=wv][b][h]
        __syncthreads();   // B2: partials published

        // ---- fold + neuron update (frozen): thread = (batch wv, h lane) ----
        double acc = 0.0;
#pragma unroll
        for (int c2 = 0; c2 < 8; ++c2)
            acc += (double)zfb[((c2 << 3) + wv) * 64 + lane];
        float rec32 = (float)acc;
        float civ = ci[((size_t)t * NB + (b0 + wv)) * HIDN + (c << 6) + lane];
        float cur = __fadd_rn(__fadd_rn(civ, rec32), 1e-4f);   // (in+rec)+I_APP
        float mc = __fmul_rn(2.5e5f, cur);                     // MU*cur
        pos = __fadd_rn(pos, __fmul_rn(1e-10f, mc));           // pos += DT*(..)
        bool zbit = __fsub_rn(pos, 2.5e-8f) > 0.0f;            // pos-W2 > 0
        pos = zbit ? 0.0f : pos;
        unsigned char* zw = (t & 1) ? zbB : zbA;
        zw[wv * HIDN + (c << 6) + lane] = zbit ? 1 : 0;        // publish u8

        // ---- group-local 8-block barrier (release via ACQ_REL add) ----
        __syncthreads();
        if (tid == 0) {
            __hip_atomic_fetch_add(myctr, 1u, __ATOMIC_ACQ_REL,
                                   __HIP_MEMORY_SCOPE_AGENT);
            const unsigned int tgt = 8u * (unsigned)(t + 1);
            while (__hip_atomic_load(myctr, __ATOMIC_ACQUIRE,
                                     __HIP_MEMORY_SCOPE_AGENT) < tgt)
                __builtin_amdgcn_s_sleep(2);
        }
        __syncthreads();   // B3: group's z_t visible (acquire fence on ctr)

        // ---- pull z_t (u8 -> float) into zf region ----
        {
            const int bb = tid >> 6, j8 = (tid & 63) * 8;
            uint2 ld = *(const uint2*)(zw + bb * HIDN + j8);
            float4 o0, o1;
            o0.x = (float)(ld.x & 255u);         o0.y = (float)((ld.x >> 8) & 255u);
            o0.z = (float)((ld.x >> 16) & 255u); o0.w = (float)(ld.x >> 24);
            o1.x = (float)(ld.y & 255u);         o1.y = (float)((ld.y >> 8) & 255u);
            o1.z = (float)((ld.y >> 16) & 255u); o1.w = (float)(ld.y >> 24);
            *(float4*)&zfb[bb * 512 + j8] = o0;
            *(float4*)&zfb[bb * 512 + j8 + 4] = o1;
        }
        __syncthreads();   // B4: zf ready for LI + next gather

        // ---- LI readout for step t (frozen chain; wave = batch wv) ----
#pragma unroll
        for (int oo = 0; oo < 2; ++oo) {
            int o = (oo == 0) ? c : (c < 2 ? 8 + c : -1);
            if (o < 0) continue;
            double part = 0.0;
#pragma unroll
            for (int c2 = 0; c2 < 8; ++c2) {
                double zfv = (double)zfb[wv * 512 + (c2 << 6) + lane];
                part = __fma_rn(zfv, (double)wout2[oo][(c2 << 6) + lane], part);
            }
#pragma unroll
            for (int off = 32; off > 0; off >>= 1) part += __shfl_down(part, off);
            if (lane == 0) {
                float inp = (float)part;
                float vvv = (oo == 0) ? vA : vB;
                float iiv = (oo == 0) ? iA : iB;
                float vn = __fadd_rn(vvv, __fmul_rn(1e-8f, __fsub_rn(iiv, vvv)));
                float t2 = __fmul_rn(2e-8f, iiv);
                float in2 = __fadd_rn(__fsub_rn(iiv, t2), inp);
                if (oo == 0) { vA = vn; iA = in2; } else { vB = vn; iB = in2; }
                out[((size_t)t * NB + (b0 + wv)) * NOUT + o] = vn;
            }
        }
    }
}

extern "C" void kernel_launch(void* const* d_in, const int* in_sizes, int n_in,
                              void* d_out, int out_size, void* d_ws, size_t ws_size,
                              hipStream_t stream) {
    (void)in_sizes; (void)n_in; (void)out_size;
    const float* x     = (const float*)d_in[0];
    const float* w_in  = (const float*)d_in[1];
    const float* w_rec = (const float*)d_in[2];
    const float* w_out = (const float*)d_in[3];
    float* out = (float*)d_out;
    float* ws  = (float*)d_ws;
    if (ws_size < (size_t)WS_FLOATS * 4) return;

    float* wT = ws + OFF_WT;
    unsigned char* zb = (unsigned char*)(ws + OFF_ZB);
    unsigned int* ctr = (unsigned int*)(ws + OFF_CTR);
    float* ci = ws + OFF_CI;

    hipLaunchKernelGGL(init_kernel, dim3((OFF_CI + 255) / 256), dim3(256), 0,
                       stream, ws, w_rec);
    hipLaunchKernelGGL(gemm_in, dim3(4, 200), dim3(256), 0, stream, x, w_in, ci);
    hipLaunchKernelGGL(fused_zf, dim3(NB), dim3(512), 0, stream,
                       ci, wT, w_out, out, zb, ctr);
}

// Round 10
// 2628.133 us; speedup vs baseline: 4.1678x; 1.0304x over previous
//
#include <hip/hip_runtime.h>
#include <cstdint>
#include <cstddef>

#define TSTEPS 100
#define NB 256
#define INF 2312
#define HIDN 512
#define NOUT 10

// ws layout (float offsets)
#define OFF_WT  0                 // 262144 floats (w_rec transposed, 1 MB)
#define OFF_ZB  262144            // 65536 floats = [2][256][512] u8 z-transit
#define OFF_CTR 327680            // 1024 u32: 32 group counters, 128B apart
#define OFF_CI  328704            // 13107200 floats (input-projection cache)
#define WS_FLOATS 13435904        // 53.7 MB

// build w_recT[j][h] = w_rec[h][j]; zero z-transit + group counters
__global__ __launch_bounds__(256) void init_kernel(float* __restrict__ ws,
                                                   const float* __restrict__ w_rec) {
    int n = blockIdx.x * 256 + threadIdx.x;
    if (n < HIDN * HIDN) {
        int j = n >> 9, h = n & 511;
        ws[n] = w_rec[h * HIDN + j];
    } else if (n < OFF_CI) {
        ws[n] = 0.0f;
    }
}

// C[r][h] = sum_k X[r][k] * Win[h][k]; per-element ascending-k fp64 chain
// `acc += (double)a * (double)b` (ARITHMETIC FROZEN: same expression, same
// operand values, same k order as all passing rounds -> bit-identical C).
// Scheduling changes only: LDS tiles stored as DOUBLE (cvt once at staging,
// killing 512 cvt/tile/thread in the inner loop) and B columns swizzled
// c -> c + (c>>3) so B-fragment ds_read_b64s hit 16 distinct banks.
__global__ __launch_bounds__(256, 2) void gemm_in(const float* __restrict__ X,
                                                  const float* __restrict__ Win,
                                                  float* __restrict__ C) {
    __shared__ double As[32][130];   // [k][row], 33.3 KB (A reads are broadcast)
    __shared__ double Bs[32][144];   // [k][swz(col)], 36.9 KB, conflict-free reads
    const int tid = threadIdx.x;
    const int tx = tid & 15;             // cols tx*8..+7
    const int ty = tid >> 4;             // rows ty*8..+7
    const int row0 = blockIdx.y * 128, col0 = blockIdx.x * 128;
    const int sr = tid >> 1, sk = (tid & 1) * 16;   // staging: row/col, k-base
    const int srz = sr + (sr >> 3);      // swizzled B col position
    float4 va[4], vb[4];
    // prologue: load tile k0=0 (gk = sk+q*4 <= 28 < INF, always in-bounds)
#pragma unroll
    for (int q = 0; q < 4; ++q) {
        int gk = sk + q * 4;
        va[q] = *(const float4*)(X + (size_t)(row0 + sr) * INF + gk);
        vb[q] = *(const float4*)(Win + (size_t)(col0 + sr) * INF + gk);
    }
    double acc[8][8] = {};
    for (int k0 = 0; k0 < INF; k0 += 32) {
        __syncthreads();   // previous compute done reading LDS
#pragma unroll
        for (int q = 0; q < 4; ++q) {
            int kc = sk + q * 4;
            As[kc + 0][sr] = (double)va[q].x; As[kc + 1][sr] = (double)va[q].y;
            As[kc + 2][sr] = (double)va[q].z; As[kc + 3][sr] = (double)va[q].w;
            Bs[kc + 0][srz] = (double)vb[q].x; Bs[kc + 1][srz] = (double)vb[q].y;
            Bs[kc + 2][srz] = (double)vb[q].z; Bs[kc + 3][srz] = (double)vb[q].w;
        }
        __syncthreads();
        // prefetch next tile into regs while computing this one
        const int kn = k0 + 32;
        if (kn < INF) {
#pragma unroll
            for (int q = 0; q < 4; ++q) {
                int gk = kn + sk + q * 4;
                float4 a = make_float4(0.f, 0.f, 0.f, 0.f);
                float4 b = make_float4(0.f, 0.f, 0.f, 0.f);
                if (gk < INF) {   // INF%4==0, gk%4==0 -> full float4 in-bounds
                    a = *(const float4*)(X + (size_t)(row0 + sr) * INF + gk);
                    b = *(const float4*)(Win + (size_t)(col0 + sr) * INF + gk);
                }
                va[q] = a; vb[q] = b;
            }
        }
#pragma unroll 4
        for (int kk = 0; kk < 32; ++kk) {
            double ad[8], bd[8];
#pragma unroll
            for (int i = 0; i < 8; ++i) ad[i] = As[kk][ty * 8 + i];
#pragma unroll
            for (int j = 0; j < 8; ++j) bd[j] = Bs[kk][9 * tx + j];  // swz(tx*8+j)
#pragma unroll
            for (int i = 0; i < 8; ++i)
#pragma unroll
                for (int j = 0; j < 8; ++j)
                    acc[i][j] += ad[i] * bd[j];
        }
    }
#pragma unroll
    for (int i = 0; i < 8; ++i) {
#pragma unroll
        for (int jj = 0; jj < 2; ++jj) {
            float4 o;
            o.x = (float)acc[i][jj * 4 + 0]; o.y = (float)acc[i][jj * 4 + 1];
            o.z = (float)acc[i][jj * 4 + 2]; o.w = (float)acc[i][jj * 4 + 3];
            *(float4*)(C + (size_t)(row0 + ty * 8 + i) * HIDN + col0 + tx * 8 + jj * 4) = o;
        }
    }
}

// Persistent fused stepper, SALU-free gather. VERBATIM R9 (passed, <=900us).
__global__ __launch_bounds__(512) void fused_zf(const float* __restrict__ ci,
        const float* __restrict__ wT, const float* __restrict__ w_out,
        float* __restrict__ out, unsigned char* __restrict__ zb,
        unsigned int* __restrict__ ctr) {
    __shared__ float zfb[4096];        // 16 KB union: zf[b][j] | fbufT[c2][b][h]
    __shared__ float wout2[2][512];    // 4 KB
    const int tid = threadIdx.x;
    const int wv = tid >> 6, lane = tid & 63;
    const int i = (int)blockIdx.x;
    const int c = (i >> 3) & 7;                    // h-chunk / group member
    const int g = (i & 7) | ((i >> 6) << 3);       // group 0..31 (co-XCD)
    const int b0 = g * 8;

    // one-time: 64 resident weights w[wv*64+qq][c*64+lane]
    float wreg[64];
#pragma unroll
    for (int qq = 0; qq < 64; ++qq)
        wreg[qq] = wT[(size_t)((wv << 6) + qq) * HIDN + (c << 6) + lane];

    if (tid < 512) {
        wout2[0][tid] = w_out[c * HIDN + tid];
        wout2[1][tid] = (c < 2) ? w_out[(8 + c) * HIDN + tid] : 0.0f;
    }
    for (int idx = tid; idx < 4096; idx += 512) zfb[idx] = 0.0f;  // z_{-1}=0
    __syncthreads();

    unsigned char* zbA = zb + (size_t)b0 * HIDN;            // [b][j] u8
    unsigned char* zbB = zb + 131072 + (size_t)b0 * HIDN;
    unsigned int* myctr = ctr + g * 32;                     // 128B apart

    float pos = 0.0f;                  // fold phase: thread = (batch wv, h lane)
    float vA = 0.f, iA = 0.f, vB = 0.f, iB = 0.f;   // LI state on lane 0

    for (int t = 0; t < TSTEPS; ++t) {
        // ---- gather: thread (word wv, h lane); zf broadcasts + fmac chains.
        float f[8] = {0.f, 0.f, 0.f, 0.f, 0.f, 0.f, 0.f, 0.f};
#pragma unroll
        for (int q4 = 0; q4 < 16; ++q4) {
            float4 z4[8];
#pragma unroll
            for (int b = 0; b < 8; ++b)
                z4[b] = *(const float4*)&zfb[b * 512 + (wv << 6) + q4 * 4];
#pragma unroll
            for (int b = 0; b < 8; ++b) {
                f[b] = __fmaf_rn(z4[b].x, wreg[q4 * 4 + 0], f[b]);
                f[b] = __fmaf_rn(z4[b].y, wreg[q4 * 4 + 1], f[b]);
                f[b] = __fmaf_rn(z4[b].z, wreg[q4 * 4 + 2], f[b]);
                f[b] = __fmaf_rn(z4[b].w, wreg[q4 * 4 + 3], f[b]);
            }
        }
        __syncthreads();   // B1: all zf reads done; region becomes fbufT
#pragma unroll
        for (int b = 0; b < 8; ++b)
            zfb[((wv << 3) + b) * 64 + lane] = f[b];   // fbufT[c2=wv][b][h]
        __syncthreads();   // B2: partials published

        // ---- fold + neuron update (frozen): thread = (batch wv, h lane) ----
        double acc = 0.0;
#pragma unroll
        for (int c2 = 0; c2 < 8; ++c2)
            acc += (double)zfb[((c2 << 3) + wv) * 64 + lane];
        float rec32 = (float)acc;
        float civ = ci[((size_t)t * NB + (b0 + wv)) * HIDN + (c << 6) + lane];
        float cur = __fadd_rn(__fadd_rn(civ, rec32), 1e-4f);   // (in+rec)+I_APP
        float mc = __fmul_rn(2.5e5f, cur);                     // MU*cur
        pos = __fadd_rn(pos, __fmul_rn(1e-10f, mc));           // pos += DT*(..)
        bool zbit = __fsub_rn(pos, 2.5e-8f) > 0.0f;            // pos-W2 > 0
        pos = zbit ? 0.0f : pos;
        unsigned char* zw = (t & 1) ? zbB : zbA;
        zw[wv * HIDN + (c << 6) + lane] = zbit ? 1 : 0;        // publish u8

        // ---- group-local 8-block barrier (release via ACQ_REL add) ----
        __syncthreads();
        if (tid == 0) {
            __hip_atomic_fetch_add(myctr, 1u, __ATOMIC_ACQ_REL,
                                   __HIP_MEMORY_SCOPE_AGENT);
            const unsigned int tgt = 8u * (unsigned)(t + 1);
            while (__hip_atomic_load(myctr, __ATOMIC_ACQUIRE,
                                     __HIP_MEMORY_SCOPE_AGENT) < tgt)
                __builtin_amdgcn_s_sleep(2);
        }
        __syncthreads();   // B3: group's z_t visible (acquire fence on ctr)

        // ---- pull z_t (u8 -> float) into zf region ----
        {
            const int bb = tid >> 6, j8 = (tid & 63) * 8;
            uint2 ld = *(const uint2*)(zw + bb * HIDN + j8);
            float4 o0, o1;
            o0.x = (float)(ld.x & 255u);         o0.y = (float)((ld.x >> 8) & 255u);
            o0.z = (float)((ld.x >> 16) & 255u); o0.w = (float)(ld.x >> 24);
            o1.x = (float)(ld.y & 255u);         o1.y = (float)((ld.y >> 8) & 255u);
            o1.z = (float)((ld.y >> 16) & 255u); o1.w = (float)(ld.y >> 24);
            *(float4*)&zfb[bb * 512 + j8] = o0;
            *(float4*)&zfb[bb * 512 + j8 + 4] = o1;
        }
        __syncthreads();   // B4: zf ready for LI + next gather

        // ---- LI readout for step t (frozen chain; wave = batch wv) ----
#pragma unroll
        for (int oo = 0; oo < 2; ++oo) {
            int o = (oo == 0) ? c : (c < 2 ? 8 + c : -1);
            if (o < 0) continue;
            double part = 0.0;
#pragma unroll
            for (int c2 = 0; c2 < 8; ++c2) {
                double zfv = (double)zfb[wv * 512 + (c2 << 6) + lane];
                part = __fma_rn(zfv, (double)wout2[oo][(c2 << 6) + lane], part);
            }
#pragma unroll
            for (int off = 32; off > 0; off >>= 1) part += __shfl_down(part, off);
            if (lane == 0) {
                float inp = (float)part;
                float vvv = (oo == 0) ? vA : vB;
                float iiv = (oo == 0) ? iA : iB;
                float vn = __fadd_rn(vvv, __fmul_rn(1e-8f, __fsub_rn(iiv, vvv)));
                float t2 = __fmul_rn(2e-8f, iiv);
                float in2 = __fadd_rn(__fsub_rn(iiv, t2), inp);
                if (oo == 0) { vA = vn; iA = in2; } else { vB = vn; iB = in2; }
                out[((size_t)t * NB + (b0 + wv)) * NOUT + o] = vn;
            }
        }
    }
}

extern "C" void kernel_launch(void* const* d_in, const int* in_sizes, int n_in,
                              void* d_out, int out_size, void* d_ws, size_t ws_size,
                              hipStream_t stream) {
    (void)in_sizes; (void)n_in; (void)out_size;
    const float* x     = (const float*)d_in[0];
    const float* w_in  = (const float*)d_in[1];
    const float* w_rec = (const float*)d_in[2];
    const float* w_out = (const float*)d_in[3];
    float* out = (float*)d_out;
    float* ws  = (float*)d_ws;
    if (ws_size < (size_t)WS_FLOATS * 4) return;

    float* wT = ws + OFF_WT;
    unsigned char* zb = (unsigned char*)(ws + OFF_ZB);
    unsigned int* ctr = (unsigned int*)(ws + OFF_CTR);
    float* ci = ws + OFF_CI;

    hipLaunchKernelGGL(init_kernel, dim3((OFF_CI + 255) / 256), dim3(256), 0,
                       stream, ws, w_rec);
    hipLaunchKernelGGL(gemm_in, dim3(4, 200), dim3(256), 0, stream, x, w_in, ci);
    hipLaunchKernelGGL(fused_zf, dim3(NB), dim3(512), 0, stream,
                       ci, wT, w_out, out, zb, ctr);
}